// Round 20
// baseline (87.520 us; speedup 1.0000x reference)
//
#include <hip/hip_runtime.h>
#include <math.h>
#include <stdint.h>

// pix_attn R19: register-halved scans -> (256,3) -> 3 waves/SIMD.
//  - R18: b128 was already emitted; flat. Model: LDS-latency bound at
//    VGPR=128 (2 waves/SIMD). Only lever left: occupancy 2->3, needs <=85.
//  - u: packed up[32]; scan1 builds {u[c0],u[c0+9]} inline per dword:
//    even c0 -> (up[c0/2]&0xffff)|(up[(c0+8)/2]&0xffff0000) (v_bfi),
//    odd  c0 -> alignbit(up[(c0+9)/2], up[(c0-1)/2], 16). 1 op, indices
//    compile-time.
//  - scan2: two c0-half passes, y2h[32] each (slot = c0, split is clean);
//    each pass folds into o[8] via re-paired blob C2 {Wv[c0],Wv[(c0+9)&63]}
//    -- no y reconstruction, same f32 sum. Tile re-read per pass (cheap).
//  - LDS 38.4KB: tile 3456 | A 2048 | B 1024 | C2 2048 | D 1024 = 9600 dw.
//  - Everything else = R16/R18: 256-thr blocks, grid 1024 (2 blocks/tile x
//    4 heads), f16 blobs + dot2/pk_fma, thinned fences, memset+atomicAdd.
//
// Scramble: f = 9*ch + l ; t = f>>6, c = f&63, (wi,wj) = (l/3, l%3).
// Pair dword: (f0, f0+9), f0 = 9*(even ch)+l; boundary iff (f0&63) >= 55.

#define GS 432      // tile group stride (words) = 6 rows * 72
#define RS 72       // tile row stride (words) = 18 cols * 4
#define A0 3456     // WqkT blob: 2048 -> [3456, 5504)
#define B0 5504     // Wk rows:   1024 -> [5504, 6528)
#define C0_ 6528    // WvT paired blob: 2048 -> [6528, 8576)
#define D0 8576     // WpT blob:  1024 -> [8576, 9600)

typedef _Float16 h2 __attribute__((ext_vector_type(2)));

static __device__ __forceinline__ h2 h2_of(uint32_t u) {
    return __builtin_bit_cast(h2, u);
}

__global__ __launch_bounds__(256, 3) void pix_attn_main(
    const float* __restrict__ x,
    const float* __restrict__ W_qk,
    const float* __restrict__ b_qk,
    const float* __restrict__ W_kv,
    const float* __restrict__ b_kv,
    const float* __restrict__ W_proj,
    const float* __restrict__ b_proj,
    float* __restrict__ out)
{
    __shared__ uint32_t smem[9600];      // 38400 B

    const int tid = threadIdx.x;
    const int j    = blockIdx.x;
    const int g_   = j >> 4;
    const int tile = g_ * 8 + (j & 7);
    const int hg   = (j >> 3) & 1;
    const int bb   = tile >> 6;
    const int t_id = tile & 63;
    const int h0r  = (t_id >> 2) << 2;
    const int w0c  = (t_id & 3) << 4;

    // ---- stage packed tile: word(g,r,cc,w) = f16(ch=8g+2w) | f16(+1) ----
    const float* xb = x + (size_t)bb * (64 * 64 * 64);
#pragma unroll
    for (int it = 0; it < 14; ++it) {
        int idx = it * 256 + tid;            // 3456 words
        if (idx < 3456) {
            int pair = idx / 108;            // 0..31
            int pix  = idx - pair * 108;
            int r    = pix / 18;
            int cc   = pix - r * 18;
            int gq   = pair >> 2;
            int w    = pair & 3;
            int gr   = h0r + r - 1;
            gr = (gr < 0) ? 1 : ((gr > 63) ? 62 : gr);
            int gc   = w0c + cc - 1;
            gc = (gc < 0) ? 1 : ((gc > 63) ? 62 : gc);
            const float* p0 = xb + ((pair * 2) << 12) + (gr << 6) + gc;
            h2 pk = { (_Float16)p0[0], (_Float16)p0[4096] };
            smem[gq * GS + r * RS + cc * 4 + w] = __builtin_bit_cast(uint32_t, pk);
        }
    }

    // ---- stage weight blobs ----
    h2* wA = (h2*)(smem + A0);    // [hh][dd 0..15][p 0..31]  : 2048
    h2* wB = (h2*)(smem + B0);    // [hh][c 0..63][dp 0..3]   : 1024
    h2* wC2 = (h2*)(smem + C0_);  // [hh][c0 0..63][dd 0..7]  : 2048 (paired)
    h2* wD = (h2*)(smem + D0);    // [jj 0..63][p 0..15]      : 1024
#pragma unroll
    for (int it = 0; it < 8; ++it) {      // blob A
        int idx = it * 256 + tid;
        int hh = idx >> 9, dd = (idx >> 5) & 15, p = idx & 31;
        int h  = hg * 4 + hh;
        int col = (dd < 8) ? (h * 8 + dd) : (64 + h * 8 + (dd & 7));
        wA[idx] = h2{ (_Float16)W_qk[(2 * p) * 128 + col],
                      (_Float16)W_qk[(2 * p + 1) * 128 + col] };
    }
#pragma unroll
    for (int it = 0; it < 4; ++it) {      // blob B
        int idx = it * 256 + tid;
        int hh = idx >> 8, c = (idx >> 2) & 63, dp = idx & 3;
        int h  = hg * 4 + hh;
        wB[idx] = h2{ (_Float16)W_kv[c * 128 + h * 8 + 2 * dp],
                      (_Float16)W_kv[c * 128 + h * 8 + 2 * dp + 1] };
    }
#pragma unroll
    for (int it = 0; it < 8; ++it) {      // blob C2 (paired rows)
        int idx = it * 256 + tid;
        int hh = idx >> 9, rem = idx & 511;
        int c0 = rem >> 3, dd = rem & 7;
        int h  = hg * 4 + hh;
        int col = 64 + h * 8 + dd;
        wC2[idx] = h2{ (_Float16)W_kv[c0 * 128 + col],
                       (_Float16)W_kv[((c0 + 9) & 63) * 128 + col] };
    }
#pragma unroll
    for (int it = 0; it < 4; ++it) {      // blob D
        int idx = it * 256 + tid;
        int jj = idx >> 4, p = idx & 15;
        wD[idx] = h2{ (_Float16)W_proj[(hg * 32 + 2 * p) * 64 + jj],
                      (_Float16)W_proj[(hg * 32 + 2 * p + 1) * 64 + jj] };
    }
    __syncthreads();

    const int wv   = __builtin_amdgcn_readfirstlane(tid >> 6);  // 0..3
    const int h8   = (hg * 4 + wv) << 3;
    const int lane = tid & 63;
    const int tr   = lane >> 4;
    const int tc   = lane & 15;
    const uint32_t* xl4 = smem + tr * RS + tc * 4;
    const float scale = 0.35355339059327373f;  // 8^-0.5

    // ---- Phase A: two half-preloads of center pairs, 16 dot2-rows ----
    float q[8], qp[8];
    {
        h2 a2[16];
        float acc16[16];
#pragma unroll
        for (int dd = 0; dd < 16; ++dd) acc16[dd] = 0.f;
#pragma unroll
        for (int half = 0; half < 2; ++half) {
#pragma unroll
            for (int g = 0; g < 4; ++g) {
                uint4 v = *(const uint4*)(xl4 + (half * 4 + g) * GS + RS + 4);
#pragma unroll
                for (int w = 0; w < 4; ++w)
                    a2[4 * g + w] = h2_of((&v.x)[w]);
            }
#pragma unroll
            for (int dd = 0; dd < 16; ++dd) {
                const uint4* wr4 =
                    (const uint4*)(wA + wv * 512 + dd * 32 + half * 16);
                float acc = acc16[dd];
#pragma unroll
                for (int p4 = 0; p4 < 4; ++p4) {
                    uint4 wv4 = wr4[p4];
#pragma unroll
                    for (int w = 0; w < 4; ++w)
                        acc = __builtin_amdgcn_fdot2(a2[p4 * 4 + w],
                                                     h2_of((&wv4.x)[w]),
                                                     acc, false);
                }
                acc16[dd] = acc;
            }
            __builtin_amdgcn_sched_barrier(0);
        }
#pragma unroll
        for (int dd = 0; dd < 16; ++dd) {
            if (dd < 8) q[dd] = b_qk[h8 + dd] + acc16[dd];
            else        qp[dd & 7] = b_qk[64 + h8 + (dd & 7)] + acc16[dd];
        }
    }
    float qv = 0.f, beta = 0.f;
#pragma unroll
    for (int d = 0; d < 8; ++d) {
        qv   = fmaf(q[d], qp[d], qv);
        beta = fmaf(q[d], b_kv[h8 + d], beta);
    }
    h2 q2[4];
#pragma unroll
    for (int dp = 0; dp < 4; ++dp)
        q2[dp] = h2{ (_Float16)q[2 * dp], (_Float16)q[2 * dp + 1] };
    __builtin_amdgcn_sched_barrier(0);

    // ---- u-phase: packed up[32] = {u[2p], u[2p+1]} (32 regs, no shift-dup)
    uint32_t up[32];
#pragma unroll
    for (int p = 0; p < 32; ++p) {
        uint4 w0 = *(const uint4*)(wB + wv * 256 + (2 * p) * 4);
        uint4 w1 = *(const uint4*)(wB + wv * 256 + (2 * p + 1) * 4);
        float s0 = 0.f, s1 = 0.f;
#pragma unroll
        for (int dp = 0; dp < 4; ++dp) {
            s0 = __builtin_amdgcn_fdot2(q2[dp], h2_of((&w0.x)[dp]), s0, false);
            s1 = __builtin_amdgcn_fdot2(q2[dp], h2_of((&w1.x)[dp]), s1, false);
        }
        up[p] = __builtin_bit_cast(uint32_t, h2{ (_Float16)s0, (_Float16)s1 });
        if ((p & 15) == 15) __builtin_amdgcn_sched_barrier(0);
    }
    __builtin_amdgcn_sched_barrier(0);

    // ---- Scan 1: lg[t] += dot2(a2, {u[c0],u[c0+9]}) built inline ----
    float lg[9];
#pragma unroll
    for (int t = 0; t < 9; ++t) lg[t] = 0.f;
#pragma unroll
    for (int g = 0; g < 8; ++g) {
#pragma unroll
        for (int l = 0; l < 9; ++l) {
            const int wi = l / 3;
            const int wj = l - wi * 3;
            uint4 v = *(const uint4*)(xl4 + g * GS + wi * RS + wj * 4);
#pragma unroll
            for (int w = 0; w < 4; ++w) {
                h2 hv = h2_of((&v.x)[w]);
                const int f0 = 9 * (8 * g + 2 * w) + l;
                const int c0 = f0 & 63;
                const int t0 = f0 >> 6;
                if (c0 < 55) {
                    uint32_t uu;
                    if (c0 & 1)
                        uu = __builtin_amdgcn_alignbit(up[(c0 + 9) >> 1],
                                                       up[(c0 - 1) >> 1], 16);
                    else
                        uu = (up[c0 >> 1] & 0xffffu) |
                             (up[(c0 + 8) >> 1] & 0xffff0000u);
                    lg[t0] = __builtin_amdgcn_fdot2(hv, h2_of(uu), lg[t0], false);
                } else {
                    const int c1 = c0 + 9 - 64;
                    float ux = (c0 & 1) ? (float)h2_of(up[c0 >> 1]).y
                                        : (float)h2_of(up[c0 >> 1]).x;
                    float uy = (c1 & 1) ? (float)h2_of(up[c1 >> 1]).y
                                        : (float)h2_of(up[c1 >> 1]).x;
                    lg[t0]     = fmaf((float)hv.x, ux, lg[t0]);
                    lg[t0 + 1] = fmaf((float)hv.y, uy, lg[t0 + 1]);
                }
            }
        }
        if (g & 1) __builtin_amdgcn_sched_barrier(0);
    }

    // ---- softmax over {9 tokens, global, qv} ----
    float pn[9], Pn = 0.f, pqv;
    {
        float lgs = 0.f, l2[11];
#pragma unroll
        for (int t = 0; t < 9; ++t) {
            lgs += lg[t];
            l2[t] = (lg[t] + beta) * scale;
        }
        l2[9]  = (lgs * (1.f / 9.f) + beta) * scale;
        l2[10] = qv;
        float m = l2[0];
#pragma unroll
        for (int i = 1; i < 11; ++i) m = fmaxf(m, l2[i]);
        float pp[11], den = 0.f;
#pragma unroll
        for (int i = 0; i < 11; ++i) { pp[i] = __expf(l2[i] - m); den += pp[i]; }
        float inv = 1.f / den;
#pragma unroll
        for (int t = 0; t < 9; ++t) {
            pn[t] = (pp[t] + pp[9] * (1.f / 9.f)) * inv;
            Pn += pn[t];
        }
        pqv = pp[10] * inv;
    }
    h2 pn2[9], pn2b[8];
#pragma unroll
    for (int t = 0; t < 9; ++t) pn2[t] = h2{ (_Float16)pn[t], (_Float16)pn[t] };
#pragma unroll
    for (int t = 0; t < 8; ++t) pn2b[t] = h2{ (_Float16)pn[t], (_Float16)pn[t + 1] };

    // ---- o init (consumes qp; qp dead afterwards) ----
    float o[8];
#pragma unroll
    for (int d = 0; d < 8; ++d)
        o[d] = fmaf(pqv, qp[d], Pn * b_kv[64 + h8 + d]);
    __builtin_amdgcn_sched_barrier(0);

    // ---- Scan 2 in two c0-half passes; fold each half via paired blob C2 ----
#pragma unroll
    for (int pass = 0; pass < 2; ++pass) {
        h2 y2h[32];
#pragma unroll
        for (int i = 0; i < 32; ++i) y2h[i] = h2{ (_Float16)0.f, (_Float16)0.f };
#pragma unroll
        for (int g = 0; g < 8; ++g) {
#pragma unroll
            for (int l = 0; l < 9; ++l) {
                const int wi = l / 3;
                const int wj = l - wi * 3;
                // compile-time: does any w of this uint4 belong to this pass?
                bool any = false;
#pragma unroll
                for (int w = 0; w < 4; ++w) {
                    const int c0w = (9 * (8 * g + 2 * w) + l) & 63;
                    if ((c0w >> 5) == pass) any = true;
                }
                if (any) {
                    uint4 v = *(const uint4*)(xl4 + g * GS + wi * RS + wj * 4);
#pragma unroll
                    for (int w = 0; w < 4; ++w) {
                        const int f0 = 9 * (8 * g + 2 * w) + l;
                        const int c0 = f0 & 63;
                        if ((c0 >> 5) != pass) continue;
                        const int t0 = f0 >> 6;
                        h2 a = h2_of((&v.x)[w]);
                        h2 m2 = (c0 < 55) ? pn2[t0] : pn2b[t0];
                        y2h[c0 & 31] = y2h[c0 & 31] + m2 * a;
                    }
                }
            }
            if (g & 1) __builtin_amdgcn_sched_barrier(0);
        }
        // fold this half: o[dd] += dot2(y2h[c0], {Wv[c0][dd], Wv[c0+9][dd]})
#pragma unroll
        for (int i = 0; i < 32; ++i) {
            const int c0 = pass * 32 + i;
            const uint4* wr4 = (const uint4*)(wC2 + wv * 512 + c0 * 8);
            uint4 w0 = wr4[0];
            uint4 w1 = wr4[1];
#pragma unroll
            for (int dd = 0; dd < 4; ++dd) {
                o[dd]     = __builtin_amdgcn_fdot2(y2h[i], h2_of((&w0.x)[dd]),
                                                   o[dd], false);
                o[dd + 4] = __builtin_amdgcn_fdot2(y2h[i], h2_of((&w1.x)[dd]),
                                                   o[dd + 4], false);
            }
            if ((i & 15) == 15) __builtin_amdgcn_sched_barrier(0);
        }
        __builtin_amdgcn_sched_barrier(0);
    }

    // ---- handoff through pre (aliased into tile region), stride 33 ----
    __syncthreads();                        // tile reads complete
    float* pre = (float*)smem;              // [pixel][33] : 2112 dw < A0
#pragma unroll
    for (int d = 0; d < 8; ++d)
        pre[lane * 33 + (wv << 3) + d] = o[d];
    __syncthreads();

    // ---- partial output projection via b128 WpT dot2-rows ----
    const int j0 = wv << 4;
    const float* pl = pre + lane * 33;
    h2 pre2[16];
#pragma unroll
    for (int p = 0; p < 16; ++p)
        pre2[p] = h2{ (_Float16)pl[2 * p], (_Float16)pl[2 * p + 1] };
    float o2[16];
#pragma unroll
    for (int jj = 0; jj < 16; ++jj) {
        const uint4* wr4 = (const uint4*)(wD + (j0 + jj) * 16);
        float acc = (hg == 0) ? b_proj[j0 + jj] : 0.f;
#pragma unroll
        for (int p4 = 0; p4 < 4; ++p4) {
            uint4 wv4 = wr4[p4];
#pragma unroll
            for (int w = 0; w < 4; ++w)
                acc = __builtin_amdgcn_fdot2(pre2[p4 * 4 + w],
                                             h2_of((&wv4.x)[w]), acc, false);
        }
        o2[jj] = acc;
    }
    float* ob = out + (size_t)bb * (64 * 64 * 64);
    const int pr = h0r + tr, pc = w0c + tc;
#pragma unroll
    for (int jj = 0; jj < 16; ++jj)
        unsafeAtomicAdd(&ob[((j0 + jj) << 12) + (pr << 6) + pc], o2[jj]);
}

extern "C" void kernel_launch(void* const* d_in, const int* in_sizes, int n_in,
                              void* d_out, int out_size, void* d_ws, size_t ws_size,
                              hipStream_t stream)
{
    const float* x      = (const float*)d_in[0];
    const float* W_qk   = (const float*)d_in[1];
    const float* b_qk   = (const float*)d_in[2];
    const float* W_kv   = (const float*)d_in[3];
    const float* b_kv   = (const float*)d_in[4];
    const float* W_proj = (const float*)d_in[5];
    const float* b_proj = (const float*)d_in[6];
    float* out = (float*)d_out;

    hipMemsetAsync(out, 0, (size_t)out_size * sizeof(float), stream);
    pix_attn_main<<<1024, 256, 0, stream>>>(x, W_qk, b_qk, W_kv, b_kv,
                                            W_proj, b_proj, out);
}

// Round 21
// 60.845 us; speedup vs baseline: 1.4384x; 1.4384x over previous
//
#include <hip/hip_runtime.h>
#include <math.h>
#include <stdint.h>

// pix_attn R20: R18 base + deeper fence thinning (per-4-group scans, no
// softmax->scan2 fence, no u->scan1 fence).
//  - R19: 4th allocator strike — 84-reg cap spills regardless of hand-counted
//    live set; occupancy locked at 2 waves/SIMD (VGPR 128). Revert to R18.
//  - Only movable term: per-wave drain stalls. R16's per-2 thinning = +6%.
//    This round: per-4 scan fences (4-deep read pipelining), scan2's first
//    reads overlap softmax VALU, scan1's first reads overlap u tail.
//  - Guards: VGPR <= 128, WRITE ~34 MB, FETCH ~20 MB (spill signature =
//    FETCH +10MB as in R14). If flat: structure is at its latency floor.
//
// Scramble: f = 9*ch + l ; t = f>>6, c = f&63, (wi,wj) = (l/3, l%3).
// Pair dword: (f0, f0+9), f0 = 9*(even ch)+l; boundary iff (f0&63) >= 55.

#define GS 432      // tile group stride (words) = 6 rows * 72
#define RS 72       // tile row stride (words) = 18 cols * 4
// LDS dword offsets (1 h2 entry = 1 dword)
#define A0 3456     // WqkT blob: 2048 entries -> [3456, 5504)
#define B0 5504     // Wk rows:   1024 entries -> [5504, 6528)
#define C0 6528     // WvT blob:  1024 entries -> [6528, 7552)
#define D0 7552     // WpT blob:  1024 entries -> [7552, 8576)

typedef _Float16 h2 __attribute__((ext_vector_type(2)));

static __device__ __forceinline__ h2 h2_of(uint32_t u) {
    return __builtin_bit_cast(h2, u);
}

__global__ __launch_bounds__(256, 2) void pix_attn_main(
    const float* __restrict__ x,
    const float* __restrict__ W_qk,
    const float* __restrict__ b_qk,
    const float* __restrict__ W_kv,
    const float* __restrict__ b_kv,
    const float* __restrict__ W_proj,
    const float* __restrict__ b_proj,
    float* __restrict__ out)
{
    __shared__ uint32_t smem[8576];      // 34304 B

    const int tid = threadIdx.x;
    const int j    = blockIdx.x;
    const int g_   = j >> 4;
    const int tile = g_ * 8 + (j & 7);
    const int hg   = (j >> 3) & 1;
    const int bb   = tile >> 6;
    const int t_id = tile & 63;
    const int h0r  = (t_id >> 2) << 2;
    const int w0c  = (t_id & 3) << 4;

    // ---- stage packed tile: word(g,r,cc,w) = f16(ch=8g+2w) | f16(+1) ----
    const float* xb = x + (size_t)bb * (64 * 64 * 64);
#pragma unroll
    for (int it = 0; it < 14; ++it) {
        int idx = it * 256 + tid;            // 3456 words
        if (idx < 3456) {
            int pair = idx / 108;            // 0..31
            int pix  = idx - pair * 108;
            int r    = pix / 18;
            int cc   = pix - r * 18;
            int gq   = pair >> 2;
            int w    = pair & 3;
            int gr   = h0r + r - 1;
            gr = (gr < 0) ? 1 : ((gr > 63) ? 62 : gr);
            int gc   = w0c + cc - 1;
            gc = (gc < 0) ? 1 : ((gc > 63) ? 62 : gc);
            const float* p0 = xb + ((pair * 2) << 12) + (gr << 6) + gc;
            h2 pk = { (_Float16)p0[0], (_Float16)p0[4096] };
            smem[gq * GS + r * RS + cc * 4 + w] = __builtin_bit_cast(uint32_t, pk);
        }
    }

    // ---- stage weight blobs (f16 pairs along channel axis) ----
    h2* wA = (h2*)(smem + A0);   // [hh][dd 0..15][p 0..31]  : 2048
    h2* wB = (h2*)(smem + B0);   // [hh][c 0..63][dp 0..3]   : 1024
    h2* wC = (h2*)(smem + C0);   // [hh][dd 0..7][p 0..31]   : 1024
    h2* wD = (h2*)(smem + D0);   // [jj 0..63][p 0..15]      : 1024
#pragma unroll
    for (int it = 0; it < 8; ++it) {      // blob A: 2048 entries
        int idx = it * 256 + tid;
        int hh = idx >> 9, dd = (idx >> 5) & 15, p = idx & 31;
        int h  = hg * 4 + hh;
        int col = (dd < 8) ? (h * 8 + dd) : (64 + h * 8 + (dd & 7));
        wA[idx] = h2{ (_Float16)W_qk[(2 * p) * 128 + col],
                      (_Float16)W_qk[(2 * p + 1) * 128 + col] };
    }
#pragma unroll
    for (int it = 0; it < 4; ++it) {      // blob B: 1024 entries
        int idx = it * 256 + tid;
        int hh = idx >> 8, c = (idx >> 2) & 63, dp = idx & 3;
        int h  = hg * 4 + hh;
        wB[idx] = h2{ (_Float16)W_kv[c * 128 + h * 8 + 2 * dp],
                      (_Float16)W_kv[c * 128 + h * 8 + 2 * dp + 1] };
    }
#pragma unroll
    for (int it = 0; it < 4; ++it) {      // blob C: 1024 entries
        int idx = it * 256 + tid;
        int hh = idx >> 8, dd = (idx >> 5) & 7, p = idx & 31;
        int h  = hg * 4 + hh;
        int col = 64 + h * 8 + dd;
        wC[idx] = h2{ (_Float16)W_kv[(2 * p) * 128 + col],
                      (_Float16)W_kv[(2 * p + 1) * 128 + col] };
    }
#pragma unroll
    for (int it = 0; it < 4; ++it) {      // blob D: 1024 entries
        int idx = it * 256 + tid;
        int jj = idx >> 4, p = idx & 15;
        wD[idx] = h2{ (_Float16)W_proj[(hg * 32 + 2 * p) * 64 + jj],
                      (_Float16)W_proj[(hg * 32 + 2 * p + 1) * 64 + jj] };
    }
    __syncthreads();

    const int wv   = __builtin_amdgcn_readfirstlane(tid >> 6);  // 0..3
    const int h8   = (hg * 4 + wv) << 3;     // this wave's head col base
    const int lane = tid & 63;
    const int tr   = lane >> 4;
    const int tc   = lane & 15;
    const uint32_t* xl4 = smem + tr * RS + tc * 4;
    const float scale = 0.35355339059327373f;  // 8^-0.5

    // ---- Phase A: two half-preloads of center pairs, 16 dot2-rows ----
    float q[8], qp[8];
    {
        h2 a2[16];
        float acc16[16];
#pragma unroll
        for (int dd = 0; dd < 16; ++dd) acc16[dd] = 0.f;
#pragma unroll
        for (int half = 0; half < 2; ++half) {
#pragma unroll
            for (int g = 0; g < 4; ++g) {
                uint4 v = *(const uint4*)(xl4 + (half * 4 + g) * GS + RS + 4);
#pragma unroll
                for (int w = 0; w < 4; ++w)
                    a2[4 * g + w] = h2_of((&v.x)[w]);
            }
#pragma unroll
            for (int dd = 0; dd < 16; ++dd) {
                const uint4* wr4 =
                    (const uint4*)(wA + wv * 512 + dd * 32 + half * 16);
                float acc = acc16[dd];
#pragma unroll
                for (int p4 = 0; p4 < 4; ++p4) {
                    uint4 wv4 = wr4[p4];
#pragma unroll
                    for (int w = 0; w < 4; ++w)
                        acc = __builtin_amdgcn_fdot2(a2[p4 * 4 + w],
                                                     h2_of((&wv4.x)[w]),
                                                     acc, false);
                }
                acc16[dd] = acc;
            }
            __builtin_amdgcn_sched_barrier(0);
        }
#pragma unroll
        for (int dd = 0; dd < 16; ++dd) {
            if (dd < 8) q[dd] = b_qk[h8 + dd] + acc16[dd];
            else        qp[dd & 7] = b_qk[64 + h8 + (dd & 7)] + acc16[dd];
        }
    }
    float qv = 0.f, beta = 0.f;
#pragma unroll
    for (int d = 0; d < 8; ++d) {
        qv   = fmaf(q[d], qp[d], qv);
        beta = fmaf(q[d], b_kv[h8 + d], beta);
    }
    h2 q2[4];
#pragma unroll
    for (int dp = 0; dp < 4; ++dp)
        q2[dp] = h2{ (_Float16)q[2 * dp], (_Float16)q[2 * dp + 1] };
    __builtin_amdgcn_sched_barrier(0);

    // ---- u-phase: u2[c] = {u[c], u[(c+9)&63]} via one uint4 per row ----
    h2 u2[64];
    float uf0[9];
#pragma unroll
    for (int c = 0; c < 64; ++c) {
        uint4 wv4 = *(const uint4*)(wB + wv * 256 + c * 4);
        float s = 0.f;
#pragma unroll
        for (int dp = 0; dp < 4; ++dp)
            s = __builtin_amdgcn_fdot2(q2[dp], h2_of((&wv4.x)[dp]), s, false);
        u2[c].x = (_Float16)s;
        if (c < 9) uf0[c] = s;
        else       u2[c - 9].y = (_Float16)s;
        if ((c & 31) == 31) __builtin_amdgcn_sched_barrier(0);
    }
#pragma unroll
    for (int c = 55; c < 64; ++c)
        u2[c].y = (_Float16)uf0[c + 9 - 64];
    // (no fence here: scan1's first reads may issue under the u tail)

    // ---- Scan 1: lg[t] += dot2(a2, u2[c0]); fenced per 4 groups ----
    float lg[9];
#pragma unroll
    for (int t = 0; t < 9; ++t) lg[t] = 0.f;
#pragma unroll
    for (int g = 0; g < 8; ++g) {
#pragma unroll
        for (int l = 0; l < 9; ++l) {
            const int wi = l / 3;
            const int wj = l - wi * 3;
            uint4 v = *(const uint4*)(xl4 + g * GS + wi * RS + wj * 4);
#pragma unroll
            for (int w = 0; w < 4; ++w) {
                h2 hv = h2_of((&v.x)[w]);
                const int f0 = 9 * (8 * g + 2 * w) + l;
                const int c0 = f0 & 63;
                const int t0 = f0 >> 6;
                if (c0 < 55) {
                    lg[t0] = __builtin_amdgcn_fdot2(hv, u2[c0], lg[t0], false);
                } else {
                    lg[t0]     = fmaf((float)hv.x, (float)u2[c0].x, lg[t0]);
                    lg[t0 + 1] = fmaf((float)hv.y, (float)u2[c0].y, lg[t0 + 1]);
                }
            }
        }
        if ((g & 3) == 3) __builtin_amdgcn_sched_barrier(0);
    }

    // ---- softmax over {9 tokens, global, qv} ----
    float pn[9], Pn = 0.f, pqv;
    {
        float lgs = 0.f, l2[11];
#pragma unroll
        for (int t = 0; t < 9; ++t) {
            lgs += lg[t];
            l2[t] = (lg[t] + beta) * scale;
        }
        l2[9]  = (lgs * (1.f / 9.f) + beta) * scale;
        l2[10] = qv;
        float m = l2[0];
#pragma unroll
        for (int i = 1; i < 11; ++i) m = fmaxf(m, l2[i]);
        float pp[11], den = 0.f;
#pragma unroll
        for (int i = 0; i < 11; ++i) { pp[i] = __expf(l2[i] - m); den += pp[i]; }
        float inv = 1.f / den;
#pragma unroll
        for (int t = 0; t < 9; ++t) {
            pn[t] = (pp[t] + pp[9] * (1.f / 9.f)) * inv;
            Pn += pn[t];
        }
        pqv = pp[10] * inv;
    }
    h2 pn2[9], pn2b[8];
#pragma unroll
    for (int t = 0; t < 9; ++t) pn2[t] = h2{ (_Float16)pn[t], (_Float16)pn[t] };
#pragma unroll
    for (int t = 0; t < 8; ++t) pn2b[t] = h2{ (_Float16)pn[t], (_Float16)pn[t + 1] };
    // (no fence here: scan2's first reads may issue under softmax VALU)

    // ---- Scan 2: y2[c0] += (pn[t0],pn[t1]) * a2 ; fenced per 4 groups ----
    h2 y2[64];
#pragma unroll
    for (int c = 0; c < 64; ++c) y2[c] = h2{ (_Float16)0.f, (_Float16)0.f };
#pragma unroll
    for (int g = 0; g < 8; ++g) {
#pragma unroll
        for (int l = 0; l < 9; ++l) {
            const int wi = l / 3;
            const int wj = l - wi * 3;
            uint4 v = *(const uint4*)(xl4 + g * GS + wi * RS + wj * 4);
#pragma unroll
            for (int w = 0; w < 4; ++w) {
                h2 a = h2_of((&v.x)[w]);
                const int f0 = 9 * (8 * g + 2 * w) + l;
                const int c0 = f0 & 63;
                const int t0 = f0 >> 6;
                h2 m2 = (c0 < 55) ? pn2[t0] : pn2b[t0];
                y2[c0] = y2[c0] + m2 * a;
            }
        }
        if ((g & 3) == 3) __builtin_amdgcn_sched_barrier(0);
    }

    // ---- pack y2c DIRECTLY from y2 (no y[64] float intermediate) ----
    h2 y2c[32];
#pragma unroll
    for (int p = 0; p < 32; ++p) {
        float ylo = (float)y2[2 * p].x     + (float)y2[(2 * p + 55) & 63].y;
        float yhi = (float)y2[2 * p + 1].x + (float)y2[(2 * p + 56) & 63].y;
        y2c[p] = h2{ (_Float16)ylo, (_Float16)yhi };
    }
    __builtin_amdgcn_sched_barrier(0);

    // ---- fold: o[dd] = b128 dot2-rows of WvT + Pn*b_v + pqv*q_ ----
    float o[8];
#pragma unroll
    for (int dd = 0; dd < 8; ++dd) {
        const uint4* wr4 = (const uint4*)(wC + wv * 256 + dd * 32);
        float acc = fmaf(pqv, qp[dd], Pn * b_kv[64 + h8 + dd]);
#pragma unroll
        for (int p4 = 0; p4 < 8; ++p4) {
            uint4 wv4 = wr4[p4];
#pragma unroll
            for (int w = 0; w < 4; ++w)
                acc = __builtin_amdgcn_fdot2(y2c[p4 * 4 + w],
                                             h2_of((&wv4.x)[w]), acc, false);
        }
        o[dd] = acc;
    }
    __builtin_amdgcn_sched_barrier(0);

    // ---- handoff through pre (aliased into tile region), stride 33 ----
    __syncthreads();                        // tile reads complete
    float* pre = (float*)smem;              // [pixel][33] : 2112 dw < A0
#pragma unroll
    for (int d = 0; d < 8; ++d)
        pre[lane * 33 + (wv << 3) + d] = o[d];
    __syncthreads();

    // ---- partial output projection via b128 WpT dot2-rows ----
    const int j0 = wv << 4;
    const float* pl = pre + lane * 33;
    h2 pre2[16];
#pragma unroll
    for (int p = 0; p < 16; ++p)
        pre2[p] = h2{ (_Float16)pl[2 * p], (_Float16)pl[2 * p + 1] };
    float o2[16];
#pragma unroll
    for (int jj = 0; jj < 16; ++jj) {
        const uint4* wr4 = (const uint4*)(wD + (j0 + jj) * 16);
        float acc = (hg == 0) ? b_proj[j0 + jj] : 0.f;
#pragma unroll
        for (int p4 = 0; p4 < 4; ++p4) {
            uint4 wv4 = wr4[p4];
#pragma unroll
            for (int w = 0; w < 4; ++w)
                acc = __builtin_amdgcn_fdot2(pre2[p4 * 4 + w],
                                             h2_of((&wv4.x)[w]), acc, false);
        }
        o2[jj] = acc;
    }
    float* ob = out + (size_t)bb * (64 * 64 * 64);
    const int pr = h0r + tr, pc = w0c + tc;
#pragma unroll
    for (int jj = 0; jj < 16; ++jj)
        unsafeAtomicAdd(&ob[((j0 + jj) << 12) + (pr << 6) + pc], o2[jj]);
}

extern "C" void kernel_launch(void* const* d_in, const int* in_sizes, int n_in,
                              void* d_out, int out_size, void* d_ws, size_t ws_size,
                              hipStream_t stream)
{
    const float* x      = (const float*)d_in[0];
    const float* W_qk   = (const float*)d_in[1];
    const float* b_qk   = (const float*)d_in[2];
    const float* W_kv   = (const float*)d_in[3];
    const float* b_kv   = (const float*)d_in[4];
    const float* W_proj = (const float*)d_in[5];
    const float* b_proj = (const float*)d_in[6];
    float* out = (float*)d_out;

    hipMemsetAsync(out, 0, (size_t)out_size * sizeof(float), stream);
    pix_attn_main<<<1024, 256, 0, stream>>>(x, W_qk, b_qk, W_kv, b_kv,
                                            W_proj, b_proj, out);
}